// Round 7
// baseline (374.283 us; speedup 1.0000x reference)
//
#include <hip/hip_runtime.h>
#include <cstdint>

// Problem constants
#define TT 512   // KVLEN
#define CC 512   // C
#define HH 8     // heads
#define NN 64    // head dim
#define BQ 32    // BATCH*QLEN
#define NB 4     // BATCH
#define TG 128   // TT/4 packed groups

__device__ __forceinline__ float sigm(float x){ return 1.f/(1.f+__expf(-x)); }

__device__ __forceinline__ float wsum(float x){
  #pragma unroll
  for (int o=32;o;o>>=1) x += __shfl_xor(x, o, 64);
  return x;
}

// 32-lane-half reduce for epilogue (offsets <=16 never cross the 32-boundary)
__device__ __forceinline__ float wsum32(float x){
  #pragma unroll
  for (int o=16;o;o>>=1) x += __shfl_xor(x, o, 64);
  return x;
}

// ---------------------------------------------------------------------------
// Batched wave64 row-sum (kept for k_svn): DPP row_ror tree + permlane16/32.
// ---------------------------------------------------------------------------
template<int NR>
__device__ __forceinline__ void rowsum64_batch(float* x){
  #pragma unroll
  for (int i=0;i<NR;i++)
    x[i] += __int_as_float(__builtin_amdgcn_mov_dpp(__float_as_int(x[i]), 0x121, 0xf, 0xf, true));
  #pragma unroll
  for (int i=0;i<NR;i++)
    x[i] += __int_as_float(__builtin_amdgcn_mov_dpp(__float_as_int(x[i]), 0x122, 0xf, 0xf, true));
  #pragma unroll
  for (int i=0;i<NR;i++)
    x[i] += __int_as_float(__builtin_amdgcn_mov_dpp(__float_as_int(x[i]), 0x124, 0xf, 0xf, true));
  #pragma unroll
  for (int i=0;i<NR;i++)
    x[i] += __int_as_float(__builtin_amdgcn_mov_dpp(__float_as_int(x[i]), 0x128, 0xf, 0xf, true));
  float y[NR];
  #pragma unroll
  for (int i=0;i<NR;i++) asm("v_mov_b32 %0, %1" : "=v"(y[i]) : "v"(x[i]));
  #pragma unroll
  for (int i=0;i<NR;i++) asm("v_permlane16_swap_b32 %0, %1" : "+v"(x[i]), "+v"(y[i]));
  #pragma unroll
  for (int i=0;i<NR;i++) x[i] += y[i];
  #pragma unroll
  for (int i=0;i<NR;i++) asm("v_mov_b32 %0, %1" : "=v"(y[i]) : "v"(x[i]));
  #pragma unroll
  for (int i=0;i<NR;i++) asm("v_permlane32_swap_b32 %0, %1" : "+v"(x[i]), "+v"(y[i]));
  #pragma unroll
  for (int i=0;i<NR;i++) x[i] += y[i];
}

// ---------------------------------------------------------------------------
// Batched 32-LANE row-sum: 4 DPP row_ror stages + permlane16_swap (rows 0<->1
// and 2<->3: stays within each 32-lane half -> two independent chains per
// wave reduce with the SAME instructions).  5 stages, no permlane32.
// ---------------------------------------------------------------------------
template<int NR>
__device__ __forceinline__ void rowsum32_batch(float* x){
  #pragma unroll
  for (int i=0;i<NR;i++)
    x[i] += __int_as_float(__builtin_amdgcn_mov_dpp(__float_as_int(x[i]), 0x121, 0xf, 0xf, true));
  #pragma unroll
  for (int i=0;i<NR;i++)
    x[i] += __int_as_float(__builtin_amdgcn_mov_dpp(__float_as_int(x[i]), 0x122, 0xf, 0xf, true));
  #pragma unroll
  for (int i=0;i<NR;i++)
    x[i] += __int_as_float(__builtin_amdgcn_mov_dpp(__float_as_int(x[i]), 0x124, 0xf, 0xf, true));
  #pragma unroll
  for (int i=0;i<NR;i++)
    x[i] += __int_as_float(__builtin_amdgcn_mov_dpp(__float_as_int(x[i]), 0x128, 0xf, 0xf, true));
  float y[NR];
  #pragma unroll
  for (int i=0;i<NR;i++) asm("v_mov_b32 %0, %1" : "=v"(y[i]) : "v"(x[i]));
  #pragma unroll
  for (int i=0;i<NR;i++) asm("v_permlane16_swap_b32 %0, %1" : "+v"(x[i]), "+v"(y[i]));
  #pragma unroll
  for (int i=0;i<NR;i++) x[i] += y[i];
}

// ---------------------------------------------------------------------------
// k_prep: per-bq small dots (32 blocks): Qw[bq,32], Qa[bq,32], gh[bq,96],
// and xr row -> workspace.
// ---------------------------------------------------------------------------
__global__ __launch_bounds__(256) void k_prep(
  const float* __restrict__ q, const float* __restrict__ kv,
  const float* __restrict__ x_r, const float* __restrict__ x_w,
  const float* __restrict__ x_a, const float* __restrict__ x_g,
  const float* __restrict__ w1, const float* __restrict__ a1,
  const float* __restrict__ g1,
  float* __restrict__ Qw, float* __restrict__ Qa,
  float* __restrict__ ghw, float* __restrict__ xrw)
{
  int bq = blockIdx.x, b = bq >> 3, tid = threadIdx.x;
  int wave = tid >> 6, lane = tid & 63;
  __shared__ float qxw[CC], qxa[CC], sxg[CC];
  for (int c = tid; c < CC; c += 256){
    float qv = q[bq*CC + c];
    float kl = kv[((size_t)b*TT + (TT-1))*CC + c];
    xrw[bq*CC + c] = kl + (qv - kl)*x_r[c];
    sxg[c] = kl + (qv - kl)*x_g[c];
    qxw[c] = qv*x_w[c];
    qxa[c] = qv*x_a[c];
  }
  __syncthreads();
  for (int dot = wave; dot < 160; dot += 4){
    const float* buf; const float* W; int ld, dd;
    if (dot < 32)      { buf = qxw; W = w1; ld = 32; dd = dot; }
    else if (dot < 64) { buf = qxa; W = a1; ld = 32; dd = dot-32; }
    else               { buf = sxg; W = g1; ld = 96; dd = dot-64; }
    float s = 0.f;
    #pragma unroll
    for (int m = 0; m < 8; m++){
      int c = m*64 + lane;
      s = fmaf(buf[c], W[c*ld + dd], s);
    }
    s = wsum(s);
    if (lane == 0){
      if (dot < 32)      Qw[bq*32 + dd] = s;
      else if (dot < 64) Qa[bq*32 + dd] = s;
      else               ghw[bq*96 + dd] = sigm(s);
    }
  }
}

// ---------------------------------------------------------------------------
// k_rg: rrow[bq,co] = xr[bq,:]@Wr[:,co], grow[bq,co] = gh[bq,:]@g2[:,co]
// ---------------------------------------------------------------------------
__global__ __launch_bounds__(256) void k_rg(
  const float* __restrict__ xrw, const float* __restrict__ ghw,
  const float* __restrict__ Wr, const float* __restrict__ g2,
  float* __restrict__ rrow, float* __restrict__ grow)
{
  int bq = blockIdx.y; int co0 = blockIdx.x*64;
  int tid = threadIdx.x, tx = tid & 63, ty = tid >> 6;
  __shared__ float sxr[CC];
  __shared__ float sgh[96];
  __shared__ float red[4][64];
  sxr[tid]     = xrw[bq*CC + tid];
  sxr[tid+256] = xrw[bq*CC + tid + 256];
  if (tid < 96) sgh[tid] = ghw[bq*96 + tid];
  __syncthreads();
  float p = 0.f;
  for (int i = 0; i < 128; i++){
    int c = ty*128 + i;
    p = fmaf(sxr[c], Wr[(size_t)c*CC + co0 + tx], p);
  }
  red[ty][tx] = p;
  float pg = 0.f;
  for (int d = ty*24; d < ty*24 + 24; d++)
    pg = fmaf(sgh[d], g2[(size_t)d*CC + co0 + tx], pg);
  __syncthreads();
  if (ty == 0)
    rrow[bq*CC + co0 + tx] = (red[0][tx]+red[1][tx])+(red[2][tx]+red[3][tx]);
  __syncthreads();
  red[ty][tx] = pg;
  __syncthreads();
  if (ty == 0)
    grow[bq*CC + co0 + tx] = (red[0][tx]+red[1][tx])+(red[2][tx]+red[3][tx]);
}

// ---------------------------------------------------------------------------
// k_shift: elementwise token-shift mix: xk, xv.  float4, coalesced.
// ---------------------------------------------------------------------------
__global__ __launch_bounds__(256) void k_shift(
  const float* __restrict__ kv, const float* __restrict__ x_k,
  const float* __restrict__ x_v,
  float* __restrict__ xk, float* __restrict__ xv)
{
  int g = blockIdx.x*256 + threadIdx.x;      // float4 index, [0, 262144)
  int bt = g >> 7, t = bt & (TT-1), c4 = g & 127;
  const float4* kv4 = (const float4*)kv;
  float4 cur = kv4[g];
  float4 sh  = t ? kv4[g-128] : make_float4(0.f,0.f,0.f,0.f);
  float4 kc  = ((const float4*)x_k)[c4];
  float4 vc  = ((const float4*)x_v)[c4];
  float4 ok, ov;
  ok.x = cur.x + (sh.x-cur.x)*kc.x; ov.x = cur.x + (sh.x-cur.x)*vc.x;
  ok.y = cur.y + (sh.y-cur.y)*kc.y; ov.y = cur.y + (sh.y-cur.y)*vc.y;
  ok.z = cur.z + (sh.z-cur.z)*kc.z; ov.z = cur.z + (sh.z-cur.z)*vc.z;
  ok.w = cur.w + (sh.w-cur.w)*kc.w; ov.w = cur.w + (sh.w-cur.w)*vc.w;
  ((float4*)xk)[g] = ok;
  ((float4*)xv)[g] = ov;
}

// ---------------------------------------------------------------------------
// k_pgemm: three [2048x512]@[512x32] products (Pw, Pa, HV), tiled.
// ---------------------------------------------------------------------------
__global__ __launch_bounds__(256) void k_pgemm(
  const float* __restrict__ kv, const float* __restrict__ xv,
  const float* __restrict__ x_w, const float* __restrict__ x_a,
  const float* __restrict__ w1, const float* __restrict__ a1,
  const float* __restrict__ v1,
  float* __restrict__ Pw, float* __restrict__ Pa, float* __restrict__ HV)
{
  int mat = blockIdx.y;
  int r0 = blockIdx.x * 64;
  const float* A = (mat == 2) ? xv : kv;
  const float* B = (mat == 0) ? w1 : (mat == 1) ? a1 : v1;
  float* O       = (mat == 0) ? Pw : (mat == 1) ? Pa : HV;
  int tid = threadIdx.x;
  __shared__ float As[32][65];
  __shared__ float Bs[32][32];
  __shared__ float scl[CC];
  for (int c = tid; c < CC; c += 256)
    scl[c] = (mat == 0) ? (1.f - x_w[c]) : (mat == 1) ? (1.f - x_a[c]) : 1.f;
  __syncthreads();
  int tx = tid & 31, ty = tid >> 5;
  float acc[8];
  #pragma unroll
  for (int i = 0; i < 8; i++) acc[i] = 0.f;
  for (int k0 = 0; k0 < 512; k0 += 32){
    #pragma unroll
    for (int p = 0; p < 8; p++){
      int e = tid + p*256;
      int kk2 = e & 31, r = e >> 5;
      As[kk2][r] = A[(size_t)(r0+r)*512 + k0 + kk2] * scl[k0 + kk2];
    }
    #pragma unroll
    for (int p = 0; p < 4; p++){
      int e = tid + p*256;
      int n = e & 31, kk2 = e >> 5;
      Bs[kk2][n] = B[(size_t)(k0+kk2)*32 + n];
    }
    __syncthreads();
    #pragma unroll
    for (int kk2 = 0; kk2 < 32; kk2++){
      float bb = Bs[kk2][tx];
      #pragma unroll
      for (int i = 0; i < 8; i++)
        acc[i] = fmaf(As[kk2][ty*8 + i], bb, acc[i]);
    }
    __syncthreads();
  }
  #pragma unroll
  for (int i = 0; i < 8; i++)
    O[(size_t)(r0 + ty*8 + i)*32 + tx] = acc[i];
}

// ---------------------------------------------------------------------------
// gemm2: two [2048x512]@[512x512] in one dispatch (blockIdx.z).
// BOTH outputs packed [b][h][tg][c][4]: z=0 -> kgP (k raw), z=1 -> vpP.
// ---------------------------------------------------------------------------
__global__ __launch_bounds__(256) void gemm2(
  const float* __restrict__ A0, const float* __restrict__ W0, float* __restrict__ kgP,
  const float* __restrict__ A1, const float* __restrict__ W1, float* __restrict__ vpP)
{
  __shared__ float As[32][68];
  __shared__ float Bs[32][64];
  int z = blockIdx.z;
  const float* A = z ? A1 : A0;
  const float* W = z ? W1 : W0;
  int tid = threadIdx.x;
  int tx = tid & 15, ty = tid >> 4;
  int m0 = blockIdx.y*64, n0 = blockIdx.x*64;
  float acc[4][4];
  #pragma unroll
  for (int i=0;i<4;i++)
    #pragma unroll
    for (int j=0;j<4;j++) acc[i][j]=0.f;

  for (int k0 = 0; k0 < 512; k0 += 32){
    #pragma unroll
    for (int i = 0; i < 8; i++){
      int e = tid + i*256;
      int kk = e & 31, m = e >> 5;
      As[kk][m] = A[(size_t)(m0+m)*512 + k0 + kk];
    }
    #pragma unroll
    for (int i = 0; i < 8; i++){
      int e = tid + i*256;
      int n = e & 63, kk = e >> 6;
      Bs[kk][n] = W[(size_t)(k0+kk)*512 + n0 + n];
    }
    __syncthreads();
    #pragma unroll
    for (int kk = 0; kk < 32; kk++){
      float a4[4], b4[4];
      #pragma unroll
      for (int i=0;i<4;i++) a4[i] = As[kk][ty*4+i];
      #pragma unroll
      for (int j=0;j<4;j++) b4[j] = Bs[kk][tx*4+j];
      #pragma unroll
      for (int i=0;i<4;i++)
        #pragma unroll
        for (int j=0;j<4;j++) acc[i][j] += a4[i]*b4[j];
    }
    __syncthreads();
  }
  // packed store: rows m..m+3 are 4 consecutive t (u=0..3)
  int m = m0 + ty*4;
  int b = m >> 9, t = m & (TT-1), tg = t >> 2;
  int h = n0 >> 6;
  float* dstB = z ? vpP : kgP;
  float4* dst = (float4*)dstB + ((size_t)(b*HH + h)*TG + tg)*64 + tx*4;
  #pragma unroll
  for (int j=0;j<4;j++)
    dst[j] = make_float4(acc[0][j],acc[1][j],acc[2][j],acc[3][j]);
}

// ---------------------------------------------------------------------------
// k_svn: fused k_kk + k_svpack.  Per (b,tg), 512 threads (one channel each).
// Reads PACKED kgP; per-wave (=per-head) norm via rowsum64_batch<4> gives
// kk = normalize(kg*k_k); sv = sigm(v0 + HV@v2).  Writes kkP, svP packed.
// ---------------------------------------------------------------------------
__global__ __launch_bounds__(512) void k_svn(
  const float* __restrict__ HV, const float* __restrict__ v2,
  const float* __restrict__ v0, const float* __restrict__ k_k,
  const float* __restrict__ kgP,
  float* __restrict__ svP, float* __restrict__ kkP)
{
  int blk = blockIdx.x;            // b*TG + tg
  int b = blk >> 7, tg = blk & (TG-1);
  int tid = threadIdx.x;           // channel c
  __shared__ float hv[4][32];
  if (tid < 128){
    int u = tid >> 5, d = tid & 31;
    hv[u][d] = HV[((size_t)(b*TT + tg*4 + u))*32 + d];
  }
  __syncthreads();
  int c = tid, h = c >> 6, cc0 = c & 63;
  size_t o = ((size_t)(b*HH + h)*TG + tg)*64 + cc0;
  float4 kg4 = ((const float4*)kgP)[o];
  float kkc = k_k[c];
  float q0 = kg4.x*kkc, q1 = kg4.y*kkc, q2 = kg4.z*kkc, q3 = kg4.w*kkc;
  float ss[4] = {q0*q0, q1*q1, q2*q2, q3*q3};
  rowsum64_batch<4>(ss);            // per-wave = per-head sum
  float4 kkq;
  kkq.x = q0 / fmaxf(sqrtf(ss[0]), 1e-12f);
  kkq.y = q1 / fmaxf(sqrtf(ss[1]), 1e-12f);
  kkq.z = q2 / fmaxf(sqrtf(ss[2]), 1e-12f);
  kkq.w = q3 / fmaxf(sqrtf(ss[3]), 1e-12f);
  ((float4*)kkP)[o] = kkq;
  float v0c = v0[c];
  float s0 = v0c, s1 = v0c, s2 = v0c, s3 = v0c;
  #pragma unroll
  for (int d = 0; d < 32; d++){
    float vc = v2[d*CC + c];
    s0 = fmaf(hv[0][d], vc, s0);
    s1 = fmaf(hv[1][d], vc, s1);
    s2 = fmaf(hv[2][d], vc, s2);
    s3 = fmaf(hv[3][d], vc, s3);
  }
  ((float4*)svP)[o] = make_float4(sigm(s0), sigm(s1), sigm(s2), sigm(s3));
}

// ---------------------------------------------------------------------------
// k_wa: per (bq,t,c): decay w and a_sig (k_final/b_vec computed in-flight
// by k_scan).  512 threads, one channel each, register-cached w2/a2 cols.
// ---------------------------------------------------------------------------
__global__ __launch_bounds__(512) void k_wa(
  const float* __restrict__ Pw, const float* __restrict__ Pa,
  const float* __restrict__ Qw, const float* __restrict__ Qa,
  const float* __restrict__ w2, const float* __restrict__ a2,
  const float* __restrict__ w0, const float* __restrict__ a0,
  float* __restrict__ wP, float* __restrict__ aP)
{
  int blk = blockIdx.x;              // bq*TG + tg
  int bq = blk >> 7, tg = blk & (TG-1), t0 = tg*4, b = bq >> 3;
  int tid = threadIdx.x;             // = channel c, 0..511
  __shared__ float sth[4][32], sal[4][32];
  if (tid < 256){
    int g = (tid >> 5) & 3, d = tid & 31;
    int pidx = ((b << 9) | (t0 + g))*32 + d;
    if (tid < 128) sth[g][d] = tanhf(Pw[pidx] + Qw[bq*32 + d]);
    else           sal[g][d] = Pa[pidx] + Qa[bq*32 + d];
  }
  __syncthreads();
  int c = tid, h = c >> 6, cc0 = c & 63;
  float wreg[32], areg[32];
  #pragma unroll
  for (int d = 0; d < 32; d++){ wreg[d] = w2[d*CC + c]; areg[d] = a2[d*CC + c]; }
  float w0c = w0[c], a0c = a0[c];
  float w4a[4], a4a[4];
  #pragma unroll
  for (int g = 0; g < 4; g++){
    float wa = 0.f, aa = 0.f;
    #pragma unroll
    for (int d = 0; d < 32; d++){
      wa = fmaf(sth[g][d], wreg[d], wa);
      aa = fmaf(sal[g][d], areg[d], aa);
    }
    w4a[g] = __expf(-0.60653066f * sigm(w0c + wa));
    a4a[g] = sigm(a0c + aa);
  }
  size_t o = ((size_t)(bq*HH + h)*TG + tg)*64 + cc0;
  ((float4*)wP)[o] = make_float4(w4a[0],w4a[1],w4a[2],w4a[3]);
  ((float4*)aP)[o] = make_float4(a4a[0],a4a[1],a4a[2],a4a[3]);
}

// ---------------------------------------------------------------------------
// K3: BACKWARD vector scan, TWO CHAINS PER WAVE (R7).
//   out += v_s (k_s . g_s);  g_{s-1} = w_s*g_s - kk_s (b_s . g_s)
// Lanes 0-31 = chain A (bq,h) pair 2*blk, lanes 32-63 = chain B (2*blk+1).
// Each lane owns 2 channels (c = 2*li, 2*li+1) -> every VALU instruction,
// including the 5-stage rowsum32 reduce, serves BOTH chains at once.  This
// halves per-chain issue cost vs R5/R6 (R6 post-mortem: scan is issue-bound
// at ~57% on its single SIMD; duration tracked instruction count).
// k,b in-flight from kg,kk,a (stream count identical either way).
// PD=2 group pipeline (8-step lookahead), sched_barrier pins prefetch.
// ---------------------------------------------------------------------------
#define SCAN_STEP2(CMP, u) do{ \
  float cw0=w4a.CMP, cw1=w4b.CMP, ca0=a4a.CMP, ca1=a4b.CMP; \
  float cg0=g4a.CMP, cg1=g4b.CMP, cn0=n4a.CMP, cn1=n4b.CMP; \
  float cp0=p4a.CMP, cp1=p4b.CMP, cs0=s4a.CMP, cs1=s4b.CMP; \
  float v0_ = fmaf(vfl[u]-cp0, cs0, cp0); \
  float v1_ = fmaf(vfl[4+u]-cp1, cs1, cp1); \
  float k0_ = cg0*fmaf(ca0-1.f, kac0, 1.f); \
  float k1_ = cg1*fmaf(ca1-1.f, kac1, 1.f); \
  float b0_ = cn0*ca0, b1_ = cn1*ca1; \
  float rr[2]; \
  rr[0] = fmaf(k1_, g1, k0_*g0); \
  rr[1] = fmaf(b1_, g1, b0_*g0); \
  rowsum32_batch<2>(rr); \
  out0 = fmaf(rr[0], v0_, out0); \
  out1 = fmaf(rr[0], v1_, out1); \
  g0 = fmaf(cw0, g0, -(cn0*rr[1])); \
  g1 = fmaf(cw1, g1, -(cn1*rr[1])); \
}while(0)

__global__ __launch_bounds__(64, 1) void k_scan(
  const float* __restrict__ wP, const float* __restrict__ aP,
  const float* __restrict__ kgP, const float* __restrict__ kkP,
  const float* __restrict__ vpP, const float* __restrict__ svP,
  const float* __restrict__ vfirst,
  const float* __restrict__ rrow, const float* __restrict__ grow,
  const float* __restrict__ r_k, const float* __restrict__ k_a,
  const float* __restrict__ ln_w, const float* __restrict__ ln_b,
  float* __restrict__ xo)
{
  int lane = threadIdx.x & 63;
  int half = lane >> 5, li = lane & 31;
  int chain = blockIdx.x*2 + half;            // (bq,h) chain id
  int bq = chain >> 3, h = chain & 7, b = bq >> 3;
  int c0 = 2*li;                              // channel within head (even)
  int ch0 = h*NN + c0;                        // global channel

  size_t bhq = ((size_t)(bq*HH + h))*TG*64 + c0;
  size_t bh  = ((size_t)(b *HH + h))*TG*64 + c0;
  const float4* wp4 = (const float4*)wP  + bhq;
  const float4* ap4 = (const float4*)aP  + bhq;
  const float4* gp4 = (const float4*)kgP + bh;
  const float4* np4 = (const float4*)kkP + bh;
  const float4* pp4 = (const float4*)vpP + bh;
  const float4* sp4 = (const float4*)svP + bh;
  const float*  pvf = vfirst + (size_t)bq*TT*CC + ch0;

  float kac0 = k_a[ch0], kac1 = k_a[ch0+1];
  float g0 = rrow[(size_t)bq*CC + ch0];       // g_{T-1} = r
  float g1 = rrow[(size_t)bq*CC + ch0 + 1];
  float out0 = 0.f, out1 = 0.f;

  constexpr int PD = 2;                // prefetch depth, groups of 4 steps
  float4 fw[PD][2], fa[PD][2], fg[PD][2], fn[PD][2], fp[PD][2], fs[PD][2];
  float  fvf[PD][8];                   // [ch0 steps 0..3 | ch1 steps 0..3]
  #pragma unroll
  for (int d = 0; d < PD; ++d){
    int gg = TG-1 - d; int go = gg*64;
    fw[d][0]=wp4[go]; fw[d][1]=wp4[go+1];
    fa[d][0]=ap4[go]; fa[d][1]=ap4[go+1];
    fg[d][0]=gp4[go]; fg[d][1]=gp4[go+1];
    fn[d][0]=np4[go]; fn[d][1]=np4[go+1];
    fp[d][0]=pp4[go]; fp[d][1]=pp4[go+1];
    fs[d][0]=sp4[go]; fs[d][1]=sp4[go+1];
    const float* pv = pvf + (size_t)(4*gg)*CC;
    #pragma unroll
    for (int u = 0; u < 4; ++u){ fvf[d][u] = pv[(size_t)u*CC]; fvf[d][4+u] = pv[(size_t)u*CC + 1]; }
  }

  #pragma unroll 1
  for (int gb = 0; gb < TG; gb += PD){
    #pragma unroll
    for (int sl = 0; sl < PD; ++sl){
      int gi = TG-1 - (gb + sl);       // current group (descending)
      // snapshot slot
      float4 w4a=fw[sl][0], w4b=fw[sl][1], a4a=fa[sl][0], a4b=fa[sl][1];
      float4 g4a=fg[sl][0], g4b=fg[sl][1], n4a=fn[sl][0], n4b=fn[sl][1];
      float4 p4a=fp[sl][0], p4b=fp[sl][1], s4a=fs[sl][0], s4b=fs[sl][1];
      float vfl[8];
      #pragma unroll
      for (int u = 0; u < 8; ++u) vfl[u] = fvf[sl][u];
      // prefetch group gi-PD into slot sl (clamped; dup loads harmless)
      int gp = gi - PD; gp = gp < 0 ? 0 : gp; int go = gp*64;
      fw[sl][0]=wp4[go]; fw[sl][1]=wp4[go+1];
      fa[sl][0]=ap4[go]; fa[sl][1]=ap4[go+1];
      fg[sl][0]=gp4[go]; fg[sl][1]=gp4[go+1];
      fn[sl][0]=np4[go]; fn[sl][1]=np4[go+1];
      fp[sl][0]=pp4[go]; fp[sl][1]=pp4[go+1];
      fs[sl][0]=sp4[go]; fs[sl][1]=sp4[go+1];
      { const float* pv = pvf + (size_t)(4*gp)*CC;
        #pragma unroll
        for (int u = 0; u < 4; ++u){ fvf[sl][u] = pv[(size_t)u*CC]; fvf[sl][4+u] = pv[(size_t)u*CC + 1]; } }
      __builtin_amdgcn_sched_barrier(0);   // pin loads in this iteration
      // 4 steps, descending t: components .w .z .y .x
      SCAN_STEP2(w, 3);
      SCAN_STEP2(z, 2);
      SCAN_STEP2(y, 1);
      SCAN_STEP2(x, 0);
    }
  }

  // epilogue (per 32-lane half = per chain): groupnorm + rk*v + gate
  {
    float mean = wsum32(out0 + out1) * (1.f/NN);
    float dv0 = out0 - mean, dv1 = out1 - mean;
    float var = wsum32(dv0*dv0 + dv1*dv1) * (1.f/NN);
    float inv = rsqrtf(var + 6.4e-4f);   // GN_EPS = 1e-5*64
    float y20 = dv0*inv * ln_w[ch0]   + ln_b[ch0];
    float y21 = dv1*inv * ln_w[ch0+1] + ln_b[ch0+1];
    int goT = (TG-1)*64;
    float4 kgT0 = gp4[goT], kgT1 = gp4[goT+1];
    float4 aT0  = ap4[goT], aT1  = ap4[goT+1];
    float kl0 = kgT0.w * fmaf(aT0.w - 1.f, kac0, 1.f);   // k_final @ T-1
    float kl1 = kgT1.w * fmaf(aT1.w - 1.f, kac1, 1.f);
    float rl0 = rrow[(size_t)bq*CC + ch0], rl1 = rrow[(size_t)bq*CC + ch0+1];
    float rk = wsum32(fmaf(rl1*kl1, r_k[ch0+1], rl0*kl0*r_k[ch0]));
    float4 pT0 = pp4[goT], pT1 = pp4[goT+1];
    float4 sT0 = sp4[goT], sT1 = sp4[goT+1];
    float vfT0 = pvf[(size_t)(TT-1)*CC], vfT1 = pvf[(size_t)(TT-1)*CC + 1];
    float vi0 = fmaf(vfT0 - pT0.w, sT0.w, pT0.w);        // v_{T-1}
    float vi1 = fmaf(vfT1 - pT1.w, sT1.w, pT1.w);
    float r0 = (y20 + rk*vi0) * grow[(size_t)bq*CC + ch0];
    float r1 = (y21 + rk*vi1) * grow[(size_t)bq*CC + ch0+1];
    xo[(size_t)bq*CC + ch0]     = r0;
    xo[(size_t)bq*CC + ch0 + 1] = r1;
  }
}

// ---------------------------------------------------------------------------
// K4: out[bq,co] = xo[bq,:] @ Wo[:,co]
// ---------------------------------------------------------------------------
__global__ __launch_bounds__(256) void k_out(
  const float* __restrict__ xo, const float* __restrict__ Wo,
  float* __restrict__ outp)
{
  int bq = blockIdx.y; int co0 = blockIdx.x*64;
  int tid = threadIdx.x, tx = tid & 63, ty = tid >> 6;
  __shared__ float row[CC];
  __shared__ float red[4][64];
  row[tid]     = xo[bq*CC + tid];
  row[tid+256] = xo[bq*CC + tid + 256];
  __syncthreads();
  float p = 0.f;
  for (int i = 0; i < 128; i++){
    int c = ty*128 + i;
    p = fmaf(row[c], Wo[(size_t)c*CC + co0 + tx], p);
  }
  red[ty][tx] = p;
  __syncthreads();
  if (ty == 0)
    outp[bq*CC + co0 + tx] = (red[0][tx]+red[1][tx])+(red[2][tx]+red[3][tx]);
}

// ---------------------------------------------------------------------------
extern "C" void kernel_launch(void* const* d_in, const int* in_sizes, int n_in,
                              void* d_out, int out_size, void* d_ws, size_t ws_size,
                              hipStream_t stream)
{
  const float* q   = (const float*)d_in[0];
  const float* kv  = (const float*)d_in[1];
  const float* vf  = (const float*)d_in[2];
  const float* x_r = (const float*)d_in[3];
  const float* x_w = (const float*)d_in[4];
  const float* x_k = (const float*)d_in[5];
  const float* x_v = (const float*)d_in[6];
  const float* x_a = (const float*)d_in[7];
  const float* x_g = (const float*)d_in[8];
  const float* w0  = (const float*)d_in[9];
  const float* w1  = (const float*)d_in[10];
  const float* w2  = (const float*)d_in[11];
  const float* a0  = (const float*)d_in[12];
  const float* a1  = (const float*)d_in[13];
  const float* a2  = (const float*)d_in[14];
  const float* v0  = (const float*)d_in[15];
  const float* v1  = (const float*)d_in[16];
  const float* v2  = (const float*)d_in[17];
  const float* g1  = (const float*)d_in[18];
  const float* g2  = (const float*)d_in[19];
  const float* k_k = (const float*)d_in[20];
  const float* k_a = (const float*)d_in[21];
  const float* r_k = (const float*)d_in[22];
  const float* Wr  = (const float*)d_in[23];
  const float* Wk  = (const float*)d_in[24];
  const float* Wv  = (const float*)d_in[25];
  const float* Wo  = (const float*)d_in[26];
  const float* lnw = (const float*)d_in[27];
  const float* lnb = (const float*)d_in[28];
  float* outp = (float*)d_out;
  float* ws = (float*)d_ws;

  // workspace layout (floats)
  float* xk  = ws + 0;         // 4*512*512
  float* xv  = ws + 1048576;
  float* kgP = ws + 2097152;   // k raw, packed [b][h][tg][c][4]
  float* vpP = ws + 3145728;   // v_pre, packed
  float* svP = ws + 4194304;   // sigmoid lerp factor, packed
  float* kkP = ws + 5242880;   // normalized kk, packed
  float* Pw  = ws + 6291456;   // 4*512*32
  float* Pa  = ws + 6356992;
  float* Qw  = ws + 6422528;   // 32*32
  float* Qa  = ws + 6423552;
  float* HV  = ws + 6424576;   // 4*512*32
  float* rr  = ws + 7473152;   // 32*512
  float* gr  = ws + 7489536;
  float* xo  = ws + 7505920;
  float* wP  = ws + 7522304;   // 32*512*512 decay, packed [bq][h][tg][c][4]
  float* aP  = ws + 15910912;  // a_sig, packed
  float* xrw = ws + 32688128;  // 32*512
  float* ghw = ws + 32704512;  // 32*96

  // v_first passthrough (tuple output #2)
  hipMemcpyAsync(outp + BQ*CC, vf,
                 (size_t)BQ*TT*CC*sizeof(float), hipMemcpyDeviceToDevice, stream);

  k_prep<<<32, 256, 0, stream>>>(q, kv, x_r, x_w, x_a, x_g, w1, a1, g1,
                                 Qw, Qa, ghw, xrw);
  k_rg<<<dim3(8, 32), 256, 0, stream>>>(xrw, ghw, Wr, g2, rr, gr);
  k_shift<<<1024, 256, 0, stream>>>(kv, x_k, x_v, xk, xv);
  gemm2<<<dim3(8, 32, 2), 256, 0, stream>>>(xk, Wk, kgP, xv, Wv, vpP);
  k_pgemm<<<dim3(32, 3), 256, 0, stream>>>(kv, xv, x_w, x_a, w1, a1, v1,
                                           Pw, Pa, HV);
  k_svn<<<NB*TG, 512, 0, stream>>>(HV, v2, v0, k_k, kgP, svP, kkP);
  k_wa<<<BQ*TG, 512, 0, stream>>>(Pw, Pa, Qw, Qa, w2, a2, w0, a0, wP, aP);
  k_scan<<<BQ*HH/2, 64, 0, stream>>>(wP, aP, kgP, kkP, vpP, svP, vf, rr, gr,
                                     r_k, k_a, lnw, lnb, xo);
  k_out<<<dim3(8, 32), 256, 0, stream>>>(xo, Wo, outp);
}